// Round 1
// baseline (177.348 us; speedup 1.0000x reference)
//
#include <hip/hip_runtime.h>

typedef __attribute__((ext_vector_type(8))) short bf16x8;
typedef __attribute__((ext_vector_type(4))) float f32x4;

#define H1_OFF 0
#define G3_OFF 0           // gfeat f32 [64][128] aliases h1 (dead by then)
#define H2_OFF 32768
#define X_OFF  65536
#define LDS_BYTES (65536 + 768)

__device__ inline unsigned short f2bf(float f){
  unsigned int u = __float_as_uint(f);
  u += 0x7FFFu + ((u >> 16) & 1u);          // round-to-nearest-even
  return (unsigned short)(u >> 16);
}

// h1/h2: bf16 [64 rows][256 cols], row stride 512B, XOR-swizzled (T2)
__device__ inline unsigned swz_h(unsigned row, unsigned colbyte){
  return row*512u + (colbyte ^ ((row & 7u) << 4));
}
// gfeat: f32 [64 rows][128 cols], row stride 512B; swizzle mixes row and col>>5
__device__ inline unsigned swz_g(unsigned row, unsigned col){
  return row*512u + ((col*4u) ^ ((((row & 7u) ^ (col >> 5)) & 7u) << 4));
}

// ---- prep: per-batch layer-1 constant ----
__global__ void prep_base1(const float* __restrict__ gf, const float* __restrict__ off,
                           const float* __restrict__ W1, const float* __restrict__ b1,
                           float* __restrict__ base1){
  int b = blockIdx.x, j = threadIdx.x;
  float acc = b1[j];
  for (int k = 0; k < 256; ++k) acc += gf[b*256 + k] * W1[k*256 + j];
  for (int d = 0; d < 3; ++d)  acc -= off[b*3 + d] * W1[(256 + d)*256 + j];
  base1[b*256 + j] = acc;
}

// ---- prep: W2/W3 -> bf16, transposed + K-step tiled for MFMA B-fragments ----
// w2t chunk s (s=0..7): [n=0..255][kk=0..31] = bf16(W2[s*32+kk][n])   (16KB each)
// w3t chunk s:          [n=0..127][kk=0..31] = bf16(W3[s*32+kk][n])   (8KB each)
// wct: [3][132] = Wc^T padded
__global__ void prep_w(const float* __restrict__ W2, const float* __restrict__ W3,
                       const float* __restrict__ Wc,
                       unsigned short* __restrict__ w2t, unsigned short* __restrict__ w3t,
                       float* __restrict__ wct){
  int e = blockIdx.x*256 + threadIdx.x;
  if (e < 65536){
    int s = e >> 13, r = e & 8191, n = r >> 5, kk = r & 31;
    w2t[e] = f2bf(W2[(s*32 + kk)*256 + n]);
  }
  if (e < 32768){
    int s = e >> 12, r = e & 4095, n = r >> 5, kk = r & 31;
    w3t[e] = f2bf(W3[(s*32 + kk)*128 + n]);
  }
  if (e < 396){
    int c = e / 132, i = e % 132;
    wct[e] = (i < 131) ? Wc[i*3 + c] : 0.0f;
  }
}

// ---- fused main kernel: 64 points/block, 4 waves ----
__global__ __launch_bounds__(256, 2) void field_main(
    const float* __restrict__ x, const float* __restrict__ rdv, const int* __restrict__ mask,
    const float* __restrict__ lf,
    const float* __restrict__ W1, const float* __restrict__ b2v, const float* __restrict__ b3v,
    const float* __restrict__ Wsv, const float* __restrict__ bsv, const float* __restrict__ bcv,
    const float* __restrict__ base1, const float* __restrict__ wct,
    const unsigned short* __restrict__ w2t, const unsigned short* __restrict__ w3t,
    float* __restrict__ out)
{
  __shared__ char lds[LDS_BYTES];
  const int tid = threadIdx.x;
  const int wid = tid >> 6, lane = tid & 63;
  const int arow = lane & 15, kgrp = lane >> 4;
  const int p0 = blockIdx.x * 64;
  const int b  = p0 >> 16;              // 65536 points per batch; BM=64 divides

  // stage x tile (64 points x 3)
  if (tid < 192) *(float*)(lds + X_OFF + tid*4) = x[p0*3 + tid];

  // this thread covers 2 adjacent h1 columns over half the rows
  const int j0 = (tid & 127) * 2, mbase = (tid >> 7) * 32;
  float2 wb  = *(const float2*)(base1 + b*256 + j0);
  float2 wx0 = *(const float2*)(W1 + 256*256 + j0);
  float2 wx1 = *(const float2*)(W1 + 257*256 + j0);
  float2 wx2 = *(const float2*)(W1 + 258*256 + j0);
  __syncthreads();

  // ---- layer 1: h1 = relu(base1[b] + x @ W1x) -> LDS bf16 (swizzled) ----
  const float* shx = (const float*)(lds + X_OFF);
  for (int mm = 0; mm < 32; ++mm){
    int m = mbase + mm;
    float x0 = shx[m*3], x1 = shx[m*3+1], x2 = shx[m*3+2];
    float ha = fmaxf(0.f, wb.x + x0*wx0.x + x1*wx1.x + x2*wx2.x);
    float hb = fmaxf(0.f, wb.y + x0*wx0.y + x1*wx1.y + x2*wx2.y);
    unsigned pk = (unsigned)f2bf(ha) | ((unsigned)f2bf(hb) << 16);
    *(unsigned*)(lds + H1_OFF + swz_h(m, j0*2)) = pk;
  }
  __syncthreads();

  // ---- layer 2: h2 = relu(h1 @ W2 + b2), wave tile = 64 rows x 64 cols ----
  f32x4 acc[16];
  #pragma unroll
  for (int i = 0; i < 16; ++i) acc[i] = (f32x4)0.f;
  const int cw = wid * 64;
  #pragma unroll 2
  for (int s = 0; s < 8; ++s){
    bf16x8 af[4], bfr[4];
    #pragma unroll
    for (int r = 0; r < 4; ++r)
      af[r] = *(const bf16x8*)(lds + H1_OFF + swz_h(r*16 + arow, s*64 + kgrp*16));
    #pragma unroll
    for (int c = 0; c < 4; ++c)
      bfr[c] = *(const bf16x8*)(w2t + s*8192 + (cw + c*16 + arow)*32 + kgrp*8);
    #pragma unroll
    for (int r = 0; r < 4; ++r)
      #pragma unroll
      for (int c = 0; c < 4; ++c)
        acc[r*4+c] = __builtin_amdgcn_mfma_f32_16x16x32_bf16(af[r], bfr[c], acc[r*4+c], 0, 0, 0);
  }
  {
    float b2r[4];
    #pragma unroll
    for (int c = 0; c < 4; ++c) b2r[c] = b2v[cw + c*16 + arow];
    #pragma unroll
    for (int r = 0; r < 4; ++r)
      #pragma unroll
      for (int c = 0; c < 4; ++c)
        #pragma unroll
        for (int j = 0; j < 4; ++j){
          int row = r*16 + kgrp*4 + j;          // C/D layout: row=(l>>4)*4+j, col=l&15
          int col = cw + c*16 + arow;
          float v = fmaxf(0.f, acc[r*4+c][j] + b2r[c]);
          *(unsigned short*)(lds + H2_OFF + swz_h(row, col*2)) = f2bf(v);
        }
  }
  __syncthreads();

  // ---- layer 3: gfeat = h2 @ W3 + b3, wave tile = 64 rows x 32 cols ----
  f32x4 acc3[8];
  #pragma unroll
  for (int i = 0; i < 8; ++i) acc3[i] = (f32x4)0.f;
  const int c3 = wid * 32;
  #pragma unroll 2
  for (int s = 0; s < 8; ++s){
    bf16x8 af[4], bfr[2];
    #pragma unroll
    for (int r = 0; r < 4; ++r)
      af[r] = *(const bf16x8*)(lds + H2_OFF + swz_h(r*16 + arow, s*64 + kgrp*16));
    #pragma unroll
    for (int c = 0; c < 2; ++c)
      bfr[c] = *(const bf16x8*)(w3t + s*4096 + (c3 + c*16 + arow)*32 + kgrp*8);
    #pragma unroll
    for (int r = 0; r < 4; ++r)
      #pragma unroll
      for (int c = 0; c < 2; ++c)
        acc3[r*2+c] = __builtin_amdgcn_mfma_f32_16x16x32_bf16(af[r], bfr[c], acc3[r*2+c], 0, 0, 0);
  }
  {
    float b3r[2];
    #pragma unroll
    for (int c = 0; c < 2; ++c) b3r[c] = b3v[c3 + c*16 + arow];
    #pragma unroll
    for (int r = 0; r < 4; ++r)
      #pragma unroll
      for (int c = 0; c < 2; ++c)
        #pragma unroll
        for (int j = 0; j < 4; ++j){
          int row = r*16 + kgrp*4 + j;
          int col = c3 + c*16 + arow;
          *(float*)(lds + G3_OFF + swz_g(row, col)) = acc3[r*2+c][j] + b3r[c];
        }
  }
  __syncthreads();

  // ---- epilogue: 4 lanes per point ----
  {
    const int g = tid >> 2, sub = tid & 3;
    const int p = p0 + g;
    float sA = 0.f, c0 = 0.f, c1 = 0.f, c2 = 0.f;
    const float* lfp = lf + (size_t)p*128 + sub*32;
    #pragma unroll
    for (int i = 0; i < 8; ++i){
      f32x4 l4 = *(const f32x4*)(lfp + i*4);
      f32x4 g4 = *(const f32x4*)(lds + G3_OFF + swz_g(g, sub*32 + i*4));
      f32x4 f4 = l4 + g4;
      f32x4 w_s = *(const f32x4*)(Wsv + sub*32 + i*4);
      f32x4 wc0 = *(const f32x4*)(wct + 0*132 + sub*32 + i*4);
      f32x4 wc1 = *(const f32x4*)(wct + 1*132 + sub*32 + i*4);
      f32x4 wc2 = *(const f32x4*)(wct + 2*132 + sub*32 + i*4);
      sA += f4[0]*w_s[0] + f4[1]*w_s[1] + f4[2]*w_s[2] + f4[3]*w_s[3];
      c0 += f4[0]*wc0[0] + f4[1]*wc0[1] + f4[2]*wc0[2] + f4[3]*wc0[3];
      c1 += f4[0]*wc1[0] + f4[1]*wc1[1] + f4[2]*wc1[2] + f4[3]*wc1[3];
      c2 += f4[0]*wc2[0] + f4[1]*wc2[1] + f4[2]*wc2[2] + f4[3]*wc2[3];
    }
    sA += __shfl_xor(sA, 1); sA += __shfl_xor(sA, 2);
    c0 += __shfl_xor(c0, 1); c0 += __shfl_xor(c0, 2);
    c1 += __shfl_xor(c1, 1); c1 += __shfl_xor(c1, 2);
    c2 += __shfl_xor(c2, 1); c2 += __shfl_xor(c2, 2);
    if (sub == 0){
      const float* rp = rdv + (p >> 5)*3;          // ray per (b,t,r), P=32
      float r0 = rp[0], r1 = rp[1], r2 = rp[2];
      float ps = sA + bsv[0] - 1.0f;
      float shape = (ps > 20.f) ? ps : log1pf(expf(ps));
      c0 += bcv[0] + r0*wct[0*132+128] + r1*wct[0*132+129] + r2*wct[0*132+130];
      c1 += bcv[1] + r0*wct[1*132+128] + r1*wct[1*132+129] + r2*wct[1*132+130];
      c2 += bcv[2] + r0*wct[2*132+128] + r1*wct[2*132+129] + r2*wct[2*132+130];
      f32x4 o;
      o[0] = shape;
      o[1] = 1.f/(1.f + expf(-c0));
      o[2] = 1.f/(1.f + expf(-c1));
      o[3] = 1.f/(1.f + expf(-c2));
      if (!mask[p]) o = (f32x4)0.f;
      *(f32x4*)(out + (size_t)p*4) = o;
    }
  }
}

extern "C" void kernel_launch(void* const* d_in, const int* in_sizes, int n_in,
                              void* d_out, int out_size, void* d_ws, size_t ws_size,
                              hipStream_t stream){
  const float* x   = (const float*)d_in[0];
  const float* rd  = (const float*)d_in[1];
  const int*   mk  = (const int*)d_in[2];
  const float* gf  = (const float*)d_in[3];
  const float* off = (const float*)d_in[4];
  const float* lf  = (const float*)d_in[5];
  const float* W1  = (const float*)d_in[6];
  const float* b1  = (const float*)d_in[7];
  const float* W2  = (const float*)d_in[8];
  const float* b2  = (const float*)d_in[9];
  const float* W3  = (const float*)d_in[10];
  const float* b3  = (const float*)d_in[11];
  const float* Ws  = (const float*)d_in[12];
  const float* bs  = (const float*)d_in[13];
  const float* Wc  = (const float*)d_in[14];
  const float* bc  = (const float*)d_in[15];

  float* base1        = (float*)d_ws;                                   // 4KB
  float* wct          = (float*)((char*)d_ws + 4096);                   // 1.6KB
  unsigned short* w2t = (unsigned short*)((char*)d_ws + 6144);          // 128KB
  unsigned short* w3t = (unsigned short*)((char*)d_ws + 6144 + 131072); // 64KB

  prep_base1<<<4, 256, 0, stream>>>(gf, off, W1, b1, base1);
  prep_w<<<256, 256, 0, stream>>>(W2, W3, Wc, w2t, w3t, wct);
  field_main<<<4096, 256, 0, stream>>>(x, rd, mk, lf, W1, b2, b3, Ws, bs, bc,
                                       base1, wct, w2t, w3t, (float*)d_out);
}

// Round 2
// 149.122 us; speedup vs baseline: 1.1893x; 1.1893x over previous
//
#include <hip/hip_runtime.h>

typedef __attribute__((ext_vector_type(8))) short bf16x8;
typedef __attribute__((ext_vector_type(4))) float f32x4;

// Single 32KB buffer reused for h1 (bf16 64x256), h2 (bf16 64x256), gfeat (f32 64x128)
#define HBUF_OFF 0
#define X_OFF    32768
#define LDS_BYTES (32768 + 768)

__device__ inline unsigned short f2bf(float f){
  unsigned int u = __float_as_uint(f);
  u += 0x7FFFu + ((u >> 16) & 1u);          // round-to-nearest-even
  return (unsigned short)(u >> 16);
}

// h1/h2: bf16 [64 rows][256 cols], row stride 512B, XOR-swizzled (T2)
__device__ inline unsigned swz_h(unsigned row, unsigned colbyte){
  return row*512u + (colbyte ^ ((row & 7u) << 4));
}
// gfeat: f32 [64 rows][128 cols], row stride 512B; swizzle mixes row and col>>5
__device__ inline unsigned swz_g(unsigned row, unsigned col){
  return row*512u + ((col*4u) ^ ((((row & 7u) ^ (col >> 5)) & 7u) << 4));
}

// ---- prep: per-batch layer-1 constant ----
__global__ void prep_base1(const float* __restrict__ gf, const float* __restrict__ off,
                           const float* __restrict__ W1, const float* __restrict__ b1,
                           float* __restrict__ base1){
  int b = blockIdx.x, j = threadIdx.x;
  float acc = b1[j];
  for (int k = 0; k < 256; ++k) acc += gf[b*256 + k] * W1[k*256 + j];
  for (int d = 0; d < 3; ++d)  acc -= off[b*3 + d] * W1[(256 + d)*256 + j];
  base1[b*256 + j] = acc;
}

// ---- prep: W2/W3 -> bf16, transposed + K-step tiled for MFMA B-fragments ----
__global__ void prep_w(const float* __restrict__ W2, const float* __restrict__ W3,
                       const float* __restrict__ Wc,
                       unsigned short* __restrict__ w2t, unsigned short* __restrict__ w3t,
                       float* __restrict__ wct){
  int e = blockIdx.x*256 + threadIdx.x;
  if (e < 65536){
    int s = e >> 13, r = e & 8191, n = r >> 5, kk = r & 31;
    w2t[e] = f2bf(W2[(s*32 + kk)*256 + n]);
  }
  if (e < 32768){
    int s = e >> 12, r = e & 4095, n = r >> 5, kk = r & 31;
    w3t[e] = f2bf(W3[(s*32 + kk)*128 + n]);
  }
  if (e < 396){
    int c = e / 132, i = e % 132;
    wct[e] = (i < 131) ? Wc[i*3 + c] : 0.0f;
  }
}

// ---- fused main kernel: 64 points/block, 4 waves, 4 blocks/CU ----
__global__ __launch_bounds__(256, 4) void field_main(
    const float* __restrict__ x, const float* __restrict__ rdv, const int* __restrict__ mask,
    const float* __restrict__ lf,
    const float* __restrict__ W1, const float* __restrict__ b2v, const float* __restrict__ b3v,
    const float* __restrict__ Wsv, const float* __restrict__ bsv, const float* __restrict__ bcv,
    const float* __restrict__ base1, const float* __restrict__ wct,
    const unsigned short* __restrict__ w2t, const unsigned short* __restrict__ w3t,
    float* __restrict__ out)
{
  __shared__ char lds[LDS_BYTES];
  const int tid = threadIdx.x;
  const int wid = tid >> 6, lane = tid & 63;
  const int arow = lane & 15, kgrp = lane >> 4;
  const int p0 = blockIdx.x * 64;
  const int b  = p0 >> 16;              // 65536 points per batch; BM=64 divides

  // early scalar prefetches (mask, ray for this thread's point)
  const int g = tid >> 2, sub = tid & 3;
  const int p = p0 + g;
  const int mk_v = mask[p];
  const float* rp = rdv + (p >> 5)*3;   // ray per (b,t,r), P=32
  const float r0 = rp[0], r1 = rp[1], r2 = rp[2];

  // stage x tile (64 points x 3)
  if (tid < 192) *(float*)(lds + X_OFF + tid*4) = x[p0*3 + tid];

  // this thread covers 2 adjacent h1 columns over half the rows
  const int j0 = (tid & 127) * 2, mbase = (tid >> 7) * 32;
  float2 wb  = *(const float2*)(base1 + b*256 + j0);
  float2 wx0 = *(const float2*)(W1 + 256*256 + j0);
  float2 wx1 = *(const float2*)(W1 + 257*256 + j0);
  float2 wx2 = *(const float2*)(W1 + 258*256 + j0);
  __syncthreads();

  // ---- layer 1: h1 = relu(base1[b] + x @ W1x) -> LDS bf16 (swizzled) ----
  const float* shx = (const float*)(lds + X_OFF);
  for (int mm = 0; mm < 32; ++mm){
    int m = mbase + mm;
    float x0 = shx[m*3], x1 = shx[m*3+1], x2 = shx[m*3+2];
    float ha = fmaxf(0.f, wb.x + x0*wx0.x + x1*wx1.x + x2*wx2.x);
    float hb = fmaxf(0.f, wb.y + x0*wx0.y + x1*wx1.y + x2*wx2.y);
    unsigned pk = (unsigned)f2bf(ha) | ((unsigned)f2bf(hb) << 16);
    *(unsigned*)(lds + HBUF_OFF + swz_h(m, j0*2)) = pk;
  }
  __syncthreads();

  // ---- layer 2: h2 = relu(h1 @ W2 + b2), wave tile = 64 rows x 64 cols ----
  f32x4 acc[16];
  #pragma unroll
  for (int i = 0; i < 16; ++i) acc[i] = (f32x4)0.f;
  const int cw = wid * 64;
  #pragma unroll 2
  for (int s = 0; s < 8; ++s){
    bf16x8 af[4], bfr[4];
    #pragma unroll
    for (int r = 0; r < 4; ++r)
      af[r] = *(const bf16x8*)(lds + HBUF_OFF + swz_h(r*16 + arow, s*64 + kgrp*16));
    #pragma unroll
    for (int c = 0; c < 4; ++c)
      bfr[c] = *(const bf16x8*)(w2t + s*8192 + (cw + c*16 + arow)*32 + kgrp*8);
    #pragma unroll
    for (int r = 0; r < 4; ++r)
      #pragma unroll
      for (int c = 0; c < 4; ++c)
        acc[r*4+c] = __builtin_amdgcn_mfma_f32_16x16x32_bf16(af[r], bfr[c], acc[r*4+c], 0, 0, 0);
  }
  __syncthreads();          // all waves done READING h1 before overwrite
  {
    float b2r[4];
    #pragma unroll
    for (int c = 0; c < 4; ++c) b2r[c] = b2v[cw + c*16 + arow];
    #pragma unroll
    for (int r = 0; r < 4; ++r)
      #pragma unroll
      for (int c = 0; c < 4; ++c)
        #pragma unroll
        for (int j = 0; j < 4; ++j){
          int row = r*16 + kgrp*4 + j;          // C/D layout: row=(l>>4)*4+j, col=l&15
          int col = cw + c*16 + arow;
          float v = fmaxf(0.f, acc[r*4+c][j] + b2r[c]);
          *(unsigned short*)(lds + HBUF_OFF + swz_h(row, col*2)) = f2bf(v);
        }
  }
  __syncthreads();

  // lf prefetch: issue now so ~900cyc HBM/L3 latency hides under layer-3 MFMAs
  f32x4 lfr[8];
  {
    const float* lfp = lf + (size_t)p*128 + sub*32;
    #pragma unroll
    for (int i = 0; i < 8; ++i) lfr[i] = *(const f32x4*)(lfp + i*4);
  }

  // ---- layer 3: gfeat = h2 @ W3 + b3, wave tile = 64 rows x 32 cols ----
  f32x4 acc3[8];
  #pragma unroll
  for (int i = 0; i < 8; ++i) acc3[i] = (f32x4)0.f;
  const int c3 = wid * 32;
  #pragma unroll 2
  for (int s = 0; s < 8; ++s){
    bf16x8 af[4], bfr[2];
    #pragma unroll
    for (int r = 0; r < 4; ++r)
      af[r] = *(const bf16x8*)(lds + HBUF_OFF + swz_h(r*16 + arow, s*64 + kgrp*16));
    #pragma unroll
    for (int c = 0; c < 2; ++c)
      bfr[c] = *(const bf16x8*)(w3t + s*4096 + (c3 + c*16 + arow)*32 + kgrp*8);
    #pragma unroll
    for (int r = 0; r < 4; ++r)
      #pragma unroll
      for (int c = 0; c < 2; ++c)
        acc3[r*2+c] = __builtin_amdgcn_mfma_f32_16x16x32_bf16(af[r], bfr[c], acc3[r*2+c], 0, 0, 0);
  }
  __syncthreads();          // all waves done READING h2 before overwrite
  {
    float b3r[2];
    #pragma unroll
    for (int c = 0; c < 2; ++c) b3r[c] = b3v[c3 + c*16 + arow];
    #pragma unroll
    for (int r = 0; r < 4; ++r)
      #pragma unroll
      for (int c = 0; c < 2; ++c)
        #pragma unroll
        for (int j = 0; j < 4; ++j){
          int row = r*16 + kgrp*4 + j;
          int col = c3 + c*16 + arow;
          *(float*)(lds + HBUF_OFF + swz_g(row, col)) = acc3[r*2+c][j] + b3r[c];
        }
  }
  __syncthreads();

  // ---- epilogue: 4 lanes per point ----
  {
    float sA = 0.f, c0 = 0.f, c1 = 0.f, c2 = 0.f;
    #pragma unroll
    for (int i = 0; i < 8; ++i){
      f32x4 g4 = *(const f32x4*)(lds + HBUF_OFF + swz_g(g, sub*32 + i*4));
      f32x4 f4 = lfr[i] + g4;
      f32x4 w_s = *(const f32x4*)(Wsv + sub*32 + i*4);
      f32x4 wc0 = *(const f32x4*)(wct + 0*132 + sub*32 + i*4);
      f32x4 wc1 = *(const f32x4*)(wct + 1*132 + sub*32 + i*4);
      f32x4 wc2 = *(const f32x4*)(wct + 2*132 + sub*32 + i*4);
      sA += f4[0]*w_s[0] + f4[1]*w_s[1] + f4[2]*w_s[2] + f4[3]*w_s[3];
      c0 += f4[0]*wc0[0] + f4[1]*wc0[1] + f4[2]*wc0[2] + f4[3]*wc0[3];
      c1 += f4[0]*wc1[0] + f4[1]*wc1[1] + f4[2]*wc1[2] + f4[3]*wc1[3];
      c2 += f4[0]*wc2[0] + f4[1]*wc2[1] + f4[2]*wc2[2] + f4[3]*wc2[3];
    }
    sA += __shfl_xor(sA, 1); sA += __shfl_xor(sA, 2);
    c0 += __shfl_xor(c0, 1); c0 += __shfl_xor(c0, 2);
    c1 += __shfl_xor(c1, 1); c1 += __shfl_xor(c1, 2);
    c2 += __shfl_xor(c2, 1); c2 += __shfl_xor(c2, 2);
    if (sub == 0){
      float ps = sA + bsv[0] - 1.0f;
      float shape = (ps > 20.f) ? ps : log1pf(expf(ps));
      c0 += bcv[0] + r0*wct[0*132+128] + r1*wct[0*132+129] + r2*wct[0*132+130];
      c1 += bcv[1] + r0*wct[1*132+128] + r1*wct[1*132+129] + r2*wct[1*132+130];
      c2 += bcv[2] + r0*wct[2*132+128] + r1*wct[2*132+129] + r2*wct[2*132+130];
      f32x4 o;
      o[0] = shape;
      o[1] = 1.f/(1.f + expf(-c0));
      o[2] = 1.f/(1.f + expf(-c1));
      o[3] = 1.f/(1.f + expf(-c2));
      if (!mk_v) o = (f32x4)0.f;
      *(f32x4*)(out + (size_t)p*4) = o;
    }
  }
}

extern "C" void kernel_launch(void* const* d_in, const int* in_sizes, int n_in,
                              void* d_out, int out_size, void* d_ws, size_t ws_size,
                              hipStream_t stream){
  const float* x   = (const float*)d_in[0];
  const float* rd  = (const float*)d_in[1];
  const int*   mk  = (const int*)d_in[2];
  const float* gf  = (const float*)d_in[3];
  const float* off = (const float*)d_in[4];
  const float* lf  = (const float*)d_in[5];
  const float* W1  = (const float*)d_in[6];
  const float* b1  = (const float*)d_in[7];
  const float* W2  = (const float*)d_in[8];
  const float* b2  = (const float*)d_in[9];
  const float* W3  = (const float*)d_in[10];
  const float* b3  = (const float*)d_in[11];
  const float* Ws  = (const float*)d_in[12];
  const float* bs  = (const float*)d_in[13];
  const float* Wc  = (const float*)d_in[14];
  const float* bc  = (const float*)d_in[15];

  float* base1        = (float*)d_ws;                                   // 4KB
  float* wct          = (float*)((char*)d_ws + 4096);                   // 1.6KB
  unsigned short* w2t = (unsigned short*)((char*)d_ws + 6144);          // 128KB
  unsigned short* w3t = (unsigned short*)((char*)d_ws + 6144 + 131072); // 64KB

  prep_base1<<<4, 256, 0, stream>>>(gf, off, W1, b1, base1);
  prep_w<<<256, 256, 0, stream>>>(W2, W3, Wc, w2t, w3t, wct);
  field_main<<<4096, 256, 0, stream>>>(x, rd, mk, lf, W1, b2, b3, Ws, bs, bc,
                                       base1, wct, w2t, w3t, (float*)d_out);
}